// Round 8
// baseline (310.636 us; speedup 1.0000x reference)
//
#include <hip/hip_runtime.h>

typedef float f4v __attribute__((ext_vector_type(4)));
typedef float f2v __attribute__((ext_vector_type(2)));
typedef short s8v __attribute__((ext_vector_type(8)));

#define TT 128
#define II 28
#define HH 200
#define BB 16        // batch rows per block
#define NT 256       // 4 waves
#define SH 232       // Hs row stride (bf16): 464 B, 16B-aligned rows; cols 224..231 = trash/pad
#define KX 224       // combined-K offset of the x block (kc7 = K 224..255)
#define CH 8         // timesteps per x chunk
#define XW (CH * BB * II)   // 3584 f32 per chunk buffer

// round-half-up f32->bf16 pair, packed: 2 adds + 1 v_perm
__device__ __forceinline__ unsigned pk_hu(float a, float b) {
    unsigned ua = __builtin_bit_cast(unsigned, a) + 0x8000u;
    unsigned ub = __builtin_bit_cast(unsigned, b) + 0x8000u;
    return __builtin_amdgcn_perm(ub, ua, 0x07060302);   // hi16(ub)<<16 | hi16(ua)
}
__device__ __forceinline__ short f2bf(float f) {
    return (short)((__builtin_bit_cast(unsigned, f) + 0x8000u) >> 16);
}

__global__ __launch_bounds__(NT, 2)
void rnn_r8(const float* __restrict__ x,
            const float* __restrict__ W_ih,
            const float* __restrict__ W_hh,
            const float* __restrict__ b_ih,
            const float* __restrict__ b_hh,
            const float* __restrict__ W_fc,
            const float* __restrict__ b_fc,
            float* __restrict__ out)
{
    // LDS: Hs 2*16*232*2 = 14848 B + Xl 2*(3584+8)*4 = 28736 B => ~42.6 KB -> 2 blocks/CU
    __shared__ __align__(16) short Hs[2][BB][SH]; // bf16 h: cols 0..199 real, 200..223 pad=0, 224..231 trash
    __shared__ __align__(16) float Xl[2][XW + 8]; // raw f32 x chunk, [t][r][c]

    const int tid  = threadIdx.x;
    const int lane = tid & 63;
    const int q    = lane >> 4;   // quad 0..3
    const int lr   = lane & 15;   // A: j-in-tile ; B/C: batch row
    const int wave = tid >> 6;    // 0..3
    const int b0   = blockIdx.x * BB;

    // UNIFORM strided tiles: wave w owns tiles w, w+4, w+8, w+12 (13..15 = zero dummies).
    // All waves issue identical instruction streams -> zero barrier skew, no branches.

    // zero both h buffers (h0 = 0, pads = 0)
    for (int i = tid; i < 2 * BB * SH / 2; i += NT) ((int*)Hs)[i] = 0;

    // ---- W~ fragments resident: A-frag(u,kc): W~[16*(wave+4u)+lr][32*kc+8*q+i]
    // W~[j][k] = W_hh[j][k] (k<200) | W_ih[j][k-224] (224<=k<252) | 0 ; dummy tiles -> all zero
    s8v Af[4][8];
    #pragma unroll
    for (int u = 0; u < 4; ++u) {
        const int j = 16 * (wave + 4 * u) + lr;
        #pragma unroll
        for (int kc = 0; kc < 8; ++kc) {
            union { short s[8]; s8v v; } tv;
            #pragma unroll
            for (int i = 0; i < 8; ++i) {
                const int k = 32 * kc + 8 * q + i;
                float w = 0.0f;
                if (j < HH) {
                    if (k < HH)                    w = W_hh[j * HH + k];
                    else if (k >= KX && k < KX+II) w = W_ih[j * II + (k - KX)];
                }
                tv.s[i] = f2bf(w);
            }
            Af[u][kc] = tv.v;
        }
    }

    // per-lane bias as C-init of chain A (C rows j = 16*t + 4*q + i)
    f4v biasv[4];
    #pragma unroll
    for (int u = 0; u < 4; ++u) {
        f4v bv = {0.f, 0.f, 0.f, 0.f};
        #pragma unroll
        for (int i = 0; i < 4; ++i) {
            const int j = 16 * (wave + 4 * u) + 4 * q + i;
            if (j < HH) bv[i] = b_ih[j] + b_hh[j];
        }
        biasv[u] = bv;
    }

    // write offsets (shorts): tiles u=0..2 always real; u=3 clamps dummies to trash col 224
    unsigned woff[4];
    #pragma unroll
    for (int u = 0; u < 4; ++u) {
        unsigned o = 16u * (wave + 4 * u) + 4 * q;
        if (u == 3 && o > 224u) o = 224u;   // v_min; uniform per wave+q
        woff[u] = o;
    }

    // ---- x DMA (waves 2,3 issue 7 global_load_lds x 16B per chunk) ----
    const int wv = wave - 2;
    long xoff[7];
    #pragma unroll
    for (int e = 0; e < 7; ++e) {
        if (wv >= 0) {
            const int m  = ((wv * 7 + e) << 6) + lane;
            const int tl = m / 112;
            const int rm = m - tl * 112;
            const int r  = rm / 7;
            const int c4 = rm - r * 7;
            xoff[e] = ((long)(b0 + r) * TT + tl) * II + c4 * 4;
        } else xoff[e] = 0;
    }
    auto load_chunk = [&](int cc) {
        if (wv >= 0) {
            float* dbase = &Xl[cc & 1][(wv * 7) * 256];
            #pragma unroll
            for (int e = 0; e < 7; ++e) {
                const float* src = x + xoff[e] + (long)cc * (CH * II);
                __builtin_amdgcn_global_load_lds(
                    (const __attribute__((address_space(1))) void*)src,
                    (__attribute__((address_space(3))) void*)(dbase + e * 256),
                    16, 0, 0);
            }
        }
    };

    load_chunk(0);
    __syncthreads();   // DMA drained + zeroed Hs visible

    for (int c = 0; c < TT / CH; ++c) {
        if (c + 1 < TT / CH) load_chunk(c + 1);
        #pragma unroll
        for (int s = 0; s < CH; ++s) {
            const int t  = c * CH + s;
            const int pb = t & 1;

            // burst-issue all 7 h B-frag reads
            s8v bf[7];
            #pragma unroll
            for (int kc = 0; kc < 7; ++kc)
                bf[kc] = *(const s8v*)&Hs[pb][lr][32 * kc + 8 * q];

            // x frag (LDS f32 -> bf16); q=3 tail cols meet zero weights
            const float* xr = &Xl[c & 1][s * (BB * II) + lr * II + 8 * q];
            const f2v x0 = *(const f2v*)(xr + 0);
            const f2v x1 = *(const f2v*)(xr + 2);
            const f2v x2 = *(const f2v*)(xr + 4);
            const f2v x3 = *(const f2v*)(xr + 6);
            union { unsigned u4[4]; s8v v; } xf;
            xf.u4[0] = pk_hu(x0.x, x0.y);
            xf.u4[1] = pk_hu(x1.x, x1.y);
            xf.u4[2] = pk_hu(x2.x, x2.y);
            xf.u4[3] = pk_hu(x3.x, x3.y);

            // split-K: chain B starts with register-fed x-MFMA (covers ds_read latency),
            // chain A starts from bias. Each chain 4 deep; merged with 4 v_add.
            f4v accA[4], accB[4];
            const f4v zero = {0.f, 0.f, 0.f, 0.f};
            #pragma unroll
            for (int u = 0; u < 4; ++u)
                accB[u] = __builtin_amdgcn_mfma_f32_16x16x32_bf16(Af[u][7], xf.v, zero, 0, 0, 0);
            #pragma unroll
            for (int kc = 0; kc < 4; ++kc) {
                #pragma unroll
                for (int u = 0; u < 4; ++u)
                    accA[u] = __builtin_amdgcn_mfma_f32_16x16x32_bf16(
                        Af[u][kc], bf[kc], (kc == 0) ? biasv[u] : accA[u], 0, 0, 0);
            }
            #pragma unroll
            for (int kc = 4; kc < 7; ++kc) {
                #pragma unroll
                for (int u = 0; u < 4; ++u)
                    accB[u] = __builtin_amdgcn_mfma_f32_16x16x32_bf16(Af[u][kc], bf[kc], accB[u], 0, 0, 0);
            }

            // merge + relu + pack + write (uniform; dummies write zeros to trash col)
            #pragma unroll
            for (int u = 0; u < 4; ++u) {
                const float r0 = fmaxf(accA[u].x + accB[u].x, 0.f);
                const float r1 = fmaxf(accA[u].y + accB[u].y, 0.f);
                const float r2 = fmaxf(accA[u].z + accB[u].z, 0.f);
                const float r3 = fmaxf(accA[u].w + accB[u].w, 0.f);
                int2 hv;
                hv.x = (int)pk_hu(r0, r1);
                hv.y = (int)pk_hu(r2, r3);
                *(int2*)&Hs[pb ^ 1][lr][woff[u]] = hv;
            }
            __syncthreads();
        }
    }

    // ---- FC epilogue: h_T is bf16 in Hs[0] (t=127 wrote pb^1 = 0) ----
    if (tid < BB * 10) {
        const int o = tid >> 4, r = tid & 15;
        float sacc = b_fc[o];
        for (int k = 0; k < HH; ++k) {
            const float hk = __builtin_bit_cast(float,
                (unsigned)((unsigned short)Hs[0][r][k]) << 16);
            sacc = fmaf(hk, W_fc[o * HH + k], sacc);
        }
        __builtin_nontemporal_store(sacc, &out[(long)(b0 + r) * 10 + o]);
    }
}

extern "C" void kernel_launch(void* const* d_in, const int* in_sizes, int n_in,
                              void* d_out, int out_size, void* d_ws, size_t ws_size,
                              hipStream_t stream) {
    const float* x    = (const float*)d_in[0];
    const float* W_ih = (const float*)d_in[1];
    const float* W_hh = (const float*)d_in[2];
    const float* b_ih = (const float*)d_in[3];
    const float* b_hh = (const float*)d_in[4];
    const float* W_fc = (const float*)d_in[5];
    const float* b_fc = (const float*)d_in[6];
    float* out = (float*)d_out;

    rnn_r8<<<dim3(8192 / BB), dim3(NT), 0, stream>>>(
        x, W_ih, W_hh, b_ih, b_hh, W_fc, b_fc, out);
}